// Round 4
// baseline (763.679 us; speedup 1.0000x reference)
//
#include <hip/hip_runtime.h>
#include <cstdint>
#include <cstddef>

// BitNet b1.58 FFN: x[8192,2048] fp32 -> h[8192,8192] (relu^2) -> out[8192,2048] fp32
// All-int8 path: exact integer GEMMs via mfma_i32_16x16x64_i8.
// R4: output is FLOAT32 (reference computes fp32 end-to-end). R2/R3 byte-identical
//     absmax proved both stagings correct -> restore global_load_lds (m97 structure).

typedef int v4i __attribute__((ext_vector_type(4)));

#define INV_WELEMS (1.0 / 16777216.0)   // 1 / (8192*2048)

__device__ __forceinline__ void async_ld16(const void* g, void* s) {
    __builtin_amdgcn_global_load_lds(
        (const __attribute__((address_space(1))) void*)(uintptr_t)g,
        (__attribute__((address_space(3))) void*)(unsigned int)(uintptr_t)s,
        16, 0, 0);
}

// ---- sum(|w|) over 16.7M fp32, fp64 accumulate ----------------------------
__global__ void absmean_kernel(const float* __restrict__ w,
                               double* __restrict__ acc) {
    __shared__ double red[256];
    int t = threadIdx.x;
    unsigned int tid = blockIdx.x * 256u + t;
    const float4* wv = (const float4*)w;
    float s = 0.f;
#pragma unroll
    for (int i = 0; i < 4; ++i) {
        float4 v = wv[tid + i * 1048576u];
        s += fabsf(v.x) + fabsf(v.y) + fabsf(v.z) + fabsf(v.w);
    }
    red[t] = (double)s;
    __syncthreads();
    for (int o = 128; o > 0; o >>= 1) {
        if (t < o) red[t] += red[t + o];
        __syncthreads();
    }
    if (t == 0) atomicAdd(acc, red[0]);
}

// ---- ternary quantize weights: q = clip(rint(w/gamma), -1, 1) -------------
__global__ void quant_w_kernel(const float* __restrict__ w,
                               int8_t* __restrict__ q,
                               const double* __restrict__ acc) {
    float gamma = (float)(acc[0] * INV_WELEMS + 1e-5);
    unsigned int tid = blockIdx.x * 256u + threadIdx.x;
    const float4* wv = (const float4*)w;
    float4 a = wv[tid * 2];
    float4 b = wv[tid * 2 + 1];
    float f[8] = {a.x, a.y, a.z, a.w, b.x, b.y, b.z, b.w};
    unsigned int lo = 0, hi = 0;
#pragma unroll
    for (int k = 0; k < 4; ++k) {
        int qv = (int)fminf(fmaxf(rintf(f[k] / gamma), -1.f), 1.f);
        lo |= ((unsigned int)(qv & 0xff)) << (8 * k);
    }
#pragma unroll
    for (int k = 0; k < 4; ++k) {
        int qv = (int)fminf(fmaxf(rintf(f[4 + k] / gamma), -1.f), 1.f);
        hi |= ((unsigned int)(qv & 0xff)) << (8 * k);
    }
    uint2 o; o.x = lo; o.y = hi;
    ((uint2*)q)[tid] = o;
}

// ---- per-token int8 quantize of x; c1[row] = gamma1 / s -------------------
__global__ void quant_x_kernel(const float* __restrict__ x,
                               int8_t* __restrict__ qx,
                               float* __restrict__ c1,
                               const double* __restrict__ accw) {
    __shared__ float red[256];
    int t = threadIdx.x;
    int row = blockIdx.x;
    const float4* xr = (const float4*)(x + (size_t)row * 2048);
    float4 a = xr[t * 2];
    float4 b = xr[t * 2 + 1];
    float f[8] = {a.x, a.y, a.z, a.w, b.x, b.y, b.z, b.w};
    float m = 0.f;
#pragma unroll
    for (int k = 0; k < 8; ++k) m = fmaxf(m, fabsf(f[k]));
    red[t] = m;
    __syncthreads();
    for (int o = 128; o > 0; o >>= 1) {
        if (t < o) red[t] = fmaxf(red[t], red[t + o]);
        __syncthreads();
    }
    float mx = fmaxf(red[0], 1e-5f);
    float s = 127.f / mx;
    unsigned int lo = 0, hi = 0;
#pragma unroll
    for (int k = 0; k < 4; ++k) {
        int qv = (int)fminf(fmaxf(rintf(f[k] * s), -128.f), 127.f);
        lo |= ((unsigned int)(qv & 0xff)) << (8 * k);
    }
#pragma unroll
    for (int k = 0; k < 4; ++k) {
        int qv = (int)fminf(fmaxf(rintf(f[4 + k] * s), -128.f), 127.f);
        hi |= ((unsigned int)(qv & 0xff)) << (8 * k);
    }
    uint2 o; o.x = lo; o.y = hi;
    ((uint2*)(qx + (size_t)row * 2048))[t] = o;
    if (t == 0) c1[row] = (float)((accw[0] * INV_WELEMS + 1e-5) / (double)s);
}

// ---- int8 GEMM, 128x128 tile, BK=64, global_load_lds staging --------------
// EPI=0: Hout[m,n] = relu(acc*rs[m])^2 (fp32).  EPI=1: Oout[m,n] = acc*rs[m] (fp32).
template <int EPI>
__global__ __launch_bounds__(256) void gemm_i8_kernel(
    const int8_t* __restrict__ A, const int8_t* __restrict__ B,
    const float* __restrict__ rs, float* __restrict__ Hout,
    float* __restrict__ Oout, int N, int K) {
    __shared__ __align__(16) int8_t sA[8192];
    __shared__ __align__(16) int8_t sB[8192];
    int t = threadIdx.x;
    int wid = t >> 6;
    int lane = t & 63;
    int lrow = lane & 15, g = lane >> 4;
    int m0 = blockIdx.y * 128, n0 = blockIdx.x * 128;
    int wm = (wid & 1) * 64, wn = (wid >> 1) * 64;

    v4i acc[4][4];
#pragma unroll
    for (int i = 0; i < 4; ++i)
#pragma unroll
        for (int j = 0; j < 4; ++j) acc[i][j] = (v4i){0, 0, 0, 0};

    const int8_t* gA = A + (size_t)(m0 + (t >> 2)) * K + (t & 3) * 16;
    const int8_t* gB = B + (size_t)(n0 + (t >> 2)) * K + (t & 3) * 16;
    int8_t* sA0 = sA + wid * 1024;
    int8_t* sA1 = sA + 4096 + wid * 1024;
    int8_t* sB0 = sB + wid * 1024;
    int8_t* sB1 = sB + 4096 + wid * 1024;
    size_t rstep = (size_t)64 * K;

    for (int k = 0; k < K; k += 64) {
        async_ld16(gA + k, sA0);
        async_ld16(gA + k + rstep, sA1);
        async_ld16(gB + k, sB0);
        async_ld16(gB + k + rstep, sB1);
        __syncthreads();
        v4i af[4], bfr[4];
#pragma unroll
        for (int i = 0; i < 4; ++i)
            af[i] = *(const v4i*)(sA + (wm + i * 16 + lrow) * 64 + g * 16);
#pragma unroll
        for (int j = 0; j < 4; ++j)
            bfr[j] = *(const v4i*)(sB + (wn + j * 16 + lrow) * 64 + g * 16);
#pragma unroll
        for (int i = 0; i < 4; ++i)
#pragma unroll
            for (int j = 0; j < 4; ++j)
                acc[i][j] = __builtin_amdgcn_mfma_i32_16x16x64_i8(af[i], bfr[j], acc[i][j], 0, 0, 0);
        __syncthreads();
    }

#pragma unroll
    for (int i = 0; i < 4; ++i) {
#pragma unroll
        for (int r = 0; r < 4; ++r) {
            int gm = m0 + wm + i * 16 + g * 4 + r;
            float c = rs[gm];
#pragma unroll
            for (int j = 0; j < 4; ++j) {
                int gn = n0 + wn + j * 16 + lrow;
                float v = (float)acc[i][j][r] * c;
                if (EPI == 0) {
                    v = fmaxf(v, 0.f);
                    Hout[(size_t)gm * N + gn] = v * v;
                } else {
                    Oout[(size_t)gm * N + gn] = v;
                }
            }
        }
    }
}

// ---- fused rowmax + int8 quantize of h; c2[row] = gamma2 / s --------------
__global__ void quant_h_kernel(const float* __restrict__ H,
                               int8_t* __restrict__ qh,
                               float* __restrict__ c2,
                               const double* __restrict__ accw) {
    __shared__ float red[256];
    int t = threadIdx.x;
    int row = blockIdx.x;
    const float4* hr = (const float4*)(H + (size_t)row * 8192);
    float4 vv[8];
    float m = 0.f;
#pragma unroll
    for (int i = 0; i < 8; ++i) {
        float4 v = hr[i * 256 + t];
        vv[i] = v;
        m = fmaxf(m, fmaxf(fmaxf(v.x, v.y), fmaxf(v.z, v.w)));
    }
    red[t] = m;
    __syncthreads();
    for (int o = 128; o > 0; o >>= 1) {
        if (t < o) red[t] = fmaxf(red[t], red[t + o]);
        __syncthreads();
    }
    float mx = fmaxf(red[0], 1e-5f);
    float s = 127.f / mx;
    unsigned int* qr = (unsigned int*)(qh + (size_t)row * 8192);
#pragma unroll
    for (int i = 0; i < 8; ++i) {
        float4 v = vv[i];
        int q0 = (int)fminf(fmaxf(rintf(v.x * s), -128.f), 127.f);
        int q1 = (int)fminf(fmaxf(rintf(v.y * s), -128.f), 127.f);
        int q2 = (int)fminf(fmaxf(rintf(v.z * s), -128.f), 127.f);
        int q3 = (int)fminf(fmaxf(rintf(v.w * s), -128.f), 127.f);
        unsigned int pk = (unsigned int)(q0 & 0xff) | ((unsigned int)(q1 & 0xff) << 8) |
                          ((unsigned int)(q2 & 0xff) << 16) | ((unsigned int)(q3 & 0xff) << 24);
        qr[i * 256 + t] = pk;
    }
    if (t == 0) c2[row] = (float)((accw[0] * INV_WELEMS + 1e-5) / (double)s);
}

extern "C" void kernel_launch(void* const* d_in, const int* in_sizes, int n_in,
                              void* d_out, int out_size, void* d_ws, size_t ws_size,
                              hipStream_t stream) {
    const float* x  = (const float*)d_in[0];
    const float* w1 = (const float*)d_in[1];
    const float* w2 = (const float*)d_in[2];
    float* out = (float*)d_out;

    char* p = (char*)d_ws;
    double* accs = (double*)p;                         // [0]=sum|w1| [1]=sum|w2|
    int8_t* qx  = (int8_t*)(p + (1ull << 20));         // 16 MB
    int8_t* qw1 = qx + (16ull << 20);                  // 16 MB
    int8_t* qw2 = qw1 + (16ull << 20);                 // 16 MB
    float* c1 = (float*)(p + (49ull << 20));           // 32 KB
    float* c2 = (float*)(p + (49ull << 20) + (1ull << 19));
    char* varbase = p + (50ull << 20);

    // adaptive M-chunking so fp32 H + int8 qh fit the workspace
    int nchunk = 1;
    while (nchunk <= 64 && (50ull << 20) + (320ull << 20) / nchunk > ws_size) nchunk <<= 1;
    if (nchunk > 64) return;  // workspace too small — fail loudly
    int CR = 8192 / nchunk;
    float* H = (float*)varbase;                        // CR x 8192 fp32
    int8_t* qh = (int8_t*)(varbase + (size_t)CR * 8192 * 4);

    hipMemsetAsync(p, 0, 256, stream);
    absmean_kernel<<<4096, 256, 0, stream>>>(w1, accs + 0);
    absmean_kernel<<<4096, 256, 0, stream>>>(w2, accs + 1);
    quant_w_kernel<<<8192, 256, 0, stream>>>(w1, qw1, accs + 0);
    quant_w_kernel<<<8192, 256, 0, stream>>>(w2, qw2, accs + 1);
    quant_x_kernel<<<8192, 256, 0, stream>>>(x, qx, c1, accs + 0);

    for (int cs = 0; cs < 8192; cs += CR) {
        gemm_i8_kernel<0><<<dim3(64, CR / 128), 256, 0, stream>>>(
            qx + (size_t)cs * 2048, qw1, c1 + cs, H, nullptr, 8192, 2048);
        quant_h_kernel<<<CR, 256, 0, stream>>>(H, qh, c2 + cs, accs + 1);
        gemm_i8_kernel<1><<<dim3(16, CR / 128), 256, 0, stream>>>(
            qh, qw2, c2 + cs, nullptr, out + (size_t)cs * 2048, 2048, 8192);
    }
}